// Round 1
// baseline (376.738 us; speedup 1.0000x reference)
//
#include <hip/hip_runtime.h>
#include <math.h>

#define NB 2
#define NN 192
#define DIMX 256
#define HID 1024
#define NROWS (NB * NN)            // 384
#define SCALING 0.17677669529663687f  // 1/sqrt(32)
#define EPS 1e-5f

// workspace layout (float offsets)
#define OFF_QKV   0
#define OFF_ATT   (OFF_QKV + NROWS * 768)        // 294912
#define OFF_TSORT (OFF_ATT + NROWS * DIMX)       // 393216
#define OFF_IDX   (OFF_TSORT + HID)              // 394240 (ints stored here)
#define OFF_DS    (OFF_IDX + HID)                // 395264
#define OFF_DC    (OFF_DS + HID * DIMX)
#define OFF_STAB  (OFF_DC + HID * DIMX)
#define OFF_CTAB  (OFF_STAB + (HID + 1) * DIMX)
// total = OFF_CTAB + (HID+1)*DIMX = 1,444,352 floats ≈ 5.8 MB

// ---------------- K1: qkv = x @ Wqkv + bqkv ----------------
__global__ __launch_bounds__(256) void qkv_kernel(
    const float* __restrict__ x, const float* __restrict__ Wqkv,
    const float* __restrict__ bqkv, float* __restrict__ qkv) {
  __shared__ float xs[4][DIMX];
  const int r0 = blockIdx.x * 4;
  const int c = threadIdx.x;
  for (int rr = 0; rr < 4; ++rr) xs[rr][c] = x[(r0 + rr) * DIMX + c];
  __syncthreads();
  float acc[4][3];
#pragma unroll
  for (int rr = 0; rr < 4; ++rr)
    for (int u = 0; u < 3; ++u) acc[rr][u] = 0.f;
  for (int k = 0; k < DIMX; ++k) {
    const float w0 = Wqkv[k * 768 + c];
    const float w1 = Wqkv[k * 768 + 256 + c];
    const float w2 = Wqkv[k * 768 + 512 + c];
#pragma unroll
    for (int rr = 0; rr < 4; ++rr) {
      const float xv = xs[rr][k];
      acc[rr][0] += xv * w0;
      acc[rr][1] += xv * w1;
      acc[rr][2] += xv * w2;
    }
  }
  const float b0 = bqkv[c], b1v = bqkv[256 + c], b2v = bqkv[512 + c];
#pragma unroll
  for (int rr = 0; rr < 4; ++rr) {
    qkv[(r0 + rr) * 768 + c] = acc[rr][0] + b0;
    qkv[(r0 + rr) * 768 + 256 + c] = acc[rr][1] + b1v;
    qkv[(r0 + rr) * 768 + 512 + c] = acc[rr][2] + b2v;
  }
}

// ------- K2: rank-sort PWL breakpoints + emit per-segment deltas -------
__global__ __launch_bounds__(1024) void sortdelta_kernel(
    const float* __restrict__ W1, const float* __restrict__ b1,
    const float* __restrict__ W2, float* __restrict__ t_sorted,
    int* __restrict__ idx_sorted, float* __restrict__ dS,
    float* __restrict__ dC) {
  __shared__ float ts[HID];
  __shared__ int sidx[HID];
  const int h = threadIdx.x;
  const float w = W1[h];
  const float t = (w != 0.f) ? (-b1[h] / w) : INFINITY;
  ts[h] = t;
  __syncthreads();
  int rank = 0;
  for (int r = 0; r < HID; ++r) {
    const float tv = ts[r];
    rank += (tv < t) || (tv == t && r < h);
  }
  t_sorted[rank] = t;
  idx_sorted[rank] = h;
  sidx[rank] = h;
  __syncthreads();
  // deltas: event s (sorted order), channel c; coalesced in c
  const int c = threadIdx.x & 255;
  const int sl = threadIdx.x >> 8;
  for (int sb = 0; sb < HID; sb += 4) {
    const int s = sb + sl;
    const int hh = sidx[s];
    const float w1v = W1[hh];
    const float sign = (w1v > 0.f) ? 1.f : -1.f;
    const float coefS = (w1v == 0.f) ? 0.f : sign * w1v;
    const float coefC = (w1v == 0.f) ? 0.f : sign * b1[hh];
    const float w2v = W2[hh * DIMX + c];
    dS[s * DIMX + c] = coefS * w2v;
    dC[s * DIMX + c] = coefC * w2v;
  }
}

// ------- K3: per-channel baseline + inclusive scan -> S/C tables -------
__global__ __launch_bounds__(1024) void scan_kernel(
    const float* __restrict__ W1, const float* __restrict__ b1,
    const float* __restrict__ W2, const float* __restrict__ b2,
    const float* __restrict__ dS, const float* __restrict__ dC,
    float* __restrict__ S_tab, float* __restrict__ C_tab) {
  const int c = blockIdx.x;
  const int s = threadIdx.x;
  __shared__ float sS[HID];
  __shared__ float sC[HID];
  // baseline: active set at d = -inf is {W1<0} plus constant {W1==0 && b1>0}
  {
    const float w = W1[s];
    const float w2v = W2[s * DIMX + c];
    float bs = 0.f, bc = 0.f;
    if (w < 0.f) {
      bs = w * w2v;
      bc = b1[s] * w2v;
    } else if (w == 0.f && b1[s] > 0.f) {
      bc = b1[s] * w2v;
    }
    sS[s] = bs;
    sC[s] = bc;
  }
  __syncthreads();
  for (int off = 512; off > 0; off >>= 1) {
    if (s < off) {
      sS[s] += sS[s + off];
      sC[s] += sC[s + off];
    }
    __syncthreads();
  }
  const float S0 = sS[0];
  const float C0 = sC[0] + b2[c];
  __syncthreads();
  // inclusive scan of deltas
  float vS = dS[s * DIMX + c];
  float vC = dC[s * DIMX + c];
  sS[s] = vS;
  sC[s] = vC;
  __syncthreads();
  for (int off = 1; off < HID; off <<= 1) {
    float aS = 0.f, aC = 0.f;
    if (s >= off) {
      aS = sS[s - off];
      aC = sC[s - off];
    }
    __syncthreads();
    sS[s] += aS;
    sC[s] += aC;
    __syncthreads();
  }
  S_tab[(s + 1) * DIMX + c] = S0 + sS[s];
  C_tab[(s + 1) * DIMX + c] = C0 + sC[s];
  if (s == 0) {
    S_tab[c] = S0;
    C_tab[c] = C0;
  }
}

// ------- K4: fused distance-attention with per-channel online softmax -------
__global__ __launch_bounds__(256) void attn_kernel(
    const float* __restrict__ pos, const int* __restrict__ mask,
    const float* __restrict__ qkv, const float* __restrict__ t_sorted,
    const float* __restrict__ S_tab, const float* __restrict__ C_tab,
    float* __restrict__ att) {
  __shared__ float tS[HID];
  __shared__ float posB[NN][3];
  __shared__ int maskB[NN];
  __shared__ float dJ[NN];
  __shared__ float decJ[NN];
  __shared__ int segJ[NN];
  __shared__ int pmJ[NN];

  const int r = blockIdx.x;
  const int b = r / NN;
  const int i = r % NN;
  const int c = threadIdx.x;

  for (int u = c; u < HID; u += 256) tS[u] = t_sorted[u];
  for (int u = c; u < NN; u += 256) {
    posB[u][0] = pos[(b * NN + u) * 3 + 0];
    posB[u][1] = pos[(b * NN + u) * 3 + 1];
    posB[u][2] = pos[(b * NN + u) * 3 + 2];
    maskB[u] = mask[b * NN + u];
  }
  __syncthreads();

  if (c < NN) {
    const int j = c;
    const float dx = posB[j][0] - posB[i][0];
    const float dy = posB[j][1] - posB[i][1];
    const float dz = posB[j][2] - posB[i][2];
    const float sq = dx * dx + dy * dy + dz * dz;
    const float d = (sq > 0.f) ? sqrtf(sq) : 0.f;
    dJ[j] = d;
    decJ[j] = __expf(-sq * 0.1f);
    // upper_bound over sorted breakpoints (PWL is continuous -> ties safe)
    int lo = 0, hi = HID;
    while (lo < hi) {
      const int mid = (lo + hi) >> 1;
      if (tS[mid] <= d) lo = mid + 1;
      else hi = mid;
    }
    segJ[j] = lo;
    pmJ[j] = maskB[i] && maskB[j];
  }
  __syncthreads();

  const float kc = qkv[(b * NN + i) * 768 + 256 + c];
  float m = -3.0e38f, l = 0.f, o = 0.f;
  for (int j = 0; j < NN; ++j) {
    const int seg = segJ[j];
    const float de = C_tab[seg * DIMX + c] + dJ[j] * S_tab[seg * DIMX + c];
    const float qv = qkv[(b * NN + j) * 768 + c];
    const float vv = qkv[(b * NN + j) * 768 + 512 + c];
    float sval = decJ[j] * (kc + de) * (qv * SCALING);
    if (pmJ[j]) sval = -1e30f;
    const float mn = fmaxf(m, sval);
    const float rr = __expf(m - mn);
    const float p = __expf(sval - mn);
    l = l * rr + p;
    o = o * rr + p * vv;
    m = mn;
  }
  att[(b * NN + i) * DIMX + c] = o / l;
}

// ------- K5: out-proj + LN1 + FFN + LN2, 4 rows per block -------
__device__ inline void blockReduce2(float v1, float v2, float* red,
                                    float* out1, float* out2) {
  for (int off = 32; off > 0; off >>= 1) {
    v1 += __shfl_down(v1, off);
    v2 += __shfl_down(v2, off);
  }
  const int wave = threadIdx.x >> 6;
  const int lane = threadIdx.x & 63;
  if (lane == 0) {
    red[wave] = v1;
    red[4 + wave] = v2;
  }
  __syncthreads();
  if (threadIdx.x == 0) {
    red[0] = red[0] + red[1] + red[2] + red[3];
    red[4] = red[4] + red[5] + red[6] + red[7];
  }
  __syncthreads();
  *out1 = red[0];
  *out2 = red[4];
  __syncthreads();
}

__global__ __launch_bounds__(256) void tail_kernel(
    const float* __restrict__ att, const float* __restrict__ x,
    const float* __restrict__ Wo, const float* __restrict__ bo,
    const float* __restrict__ ln1g, const float* __restrict__ ln1b,
    const float* __restrict__ Wf1, const float* __restrict__ bf1,
    const float* __restrict__ Wf2, const float* __restrict__ bf2,
    const float* __restrict__ ln2g, const float* __restrict__ ln2b,
    float* __restrict__ out) {
  __shared__ float atts[4][DIMX];
  __shared__ float x1s[4][DIMX];
  __shared__ float hids[4][HID];
  __shared__ float red[8];
  const int r0 = blockIdx.x * 4;
  const int c = threadIdx.x;

  float xr[4];
#pragma unroll
  for (int rr = 0; rr < 4; ++rr) {
    atts[rr][c] = att[(r0 + rr) * DIMX + c];
    xr[rr] = x[(r0 + rr) * DIMX + c];
  }
  __syncthreads();

  float a[4] = {0.f, 0.f, 0.f, 0.f};
  for (int k = 0; k < DIMX; ++k) {
    const float wv = Wo[k * DIMX + c];
#pragma unroll
    for (int rr = 0; rr < 4; ++rr) a[rr] += atts[rr][k] * wv;
  }
  const float bov = bo[c], g1 = ln1g[c], be1 = ln1b[c];
  float t1[4];
#pragma unroll
  for (int rr = 0; rr < 4; ++rr) t1[rr] = xr[rr] + a[rr] + bov;

#pragma unroll
  for (int rr = 0; rr < 4; ++rr) {
    float s1, s2;
    blockReduce2(t1[rr], t1[rr] * t1[rr], red, &s1, &s2);
    const float mu = s1 * (1.f / DIMX);
    const float var = s2 * (1.f / DIMX) - mu * mu;
    const float x1 = (t1[rr] - mu) * rsqrtf(var + EPS) * g1 + be1;
    x1s[rr][c] = x1;
  }
  __syncthreads();

  float hacc[4][4];
#pragma unroll
  for (int rr = 0; rr < 4; ++rr)
    for (int u = 0; u < 4; ++u) hacc[rr][u] = 0.f;
  for (int k = 0; k < DIMX; ++k) {
    float wv[4];
#pragma unroll
    for (int u = 0; u < 4; ++u) wv[u] = Wf1[k * HID + u * 256 + c];
#pragma unroll
    for (int rr = 0; rr < 4; ++rr) {
      const float xv = x1s[rr][k];
#pragma unroll
      for (int u = 0; u < 4; ++u) hacc[rr][u] += xv * wv[u];
    }
  }
#pragma unroll
  for (int u = 0; u < 4; ++u) {
    const float bf = bf1[u * 256 + c];
#pragma unroll
    for (int rr = 0; rr < 4; ++rr)
      hids[rr][u * 256 + c] = fmaxf(hacc[rr][u] + bf, 0.f);
  }
  __syncthreads();

  float o2[4] = {0.f, 0.f, 0.f, 0.f};
  for (int t = 0; t < HID; ++t) {
    const float wv = Wf2[t * DIMX + c];
#pragma unroll
    for (int rr = 0; rr < 4; ++rr) o2[rr] += hids[rr][t] * wv;
  }
  const float bf2v = bf2[c], g2 = ln2g[c], be2 = ln2b[c];
#pragma unroll
  for (int rr = 0; rr < 4; ++rr) {
    const float t2 = x1s[rr][c] + o2[rr] + bf2v;
    float s1, s2;
    blockReduce2(t2, t2 * t2, red, &s1, &s2);
    const float mu = s1 * (1.f / DIMX);
    const float var = s2 * (1.f / DIMX) - mu * mu;
    out[(r0 + rr) * DIMX + c] = (t2 - mu) * rsqrtf(var + EPS) * g2 + be2;
  }
}

extern "C" void kernel_launch(void* const* d_in, const int* in_sizes, int n_in,
                              void* d_out, int out_size, void* d_ws,
                              size_t ws_size, hipStream_t stream) {
  const float* x = (const float*)d_in[0];
  const float* pos = (const float*)d_in[1];
  const int* mask = (const int*)d_in[2];
  const float* Wqkv = (const float*)d_in[3];
  const float* bqkv = (const float*)d_in[4];
  const float* W1 = (const float*)d_in[5];
  const float* b1 = (const float*)d_in[6];
  const float* W2 = (const float*)d_in[7];
  const float* b2 = (const float*)d_in[8];
  const float* Wo = (const float*)d_in[9];
  const float* bo = (const float*)d_in[10];
  const float* ln1g = (const float*)d_in[11];
  const float* ln1b = (const float*)d_in[12];
  const float* Wf1 = (const float*)d_in[13];
  const float* bf1 = (const float*)d_in[14];
  const float* Wf2 = (const float*)d_in[15];
  const float* bf2 = (const float*)d_in[16];
  const float* ln2g = (const float*)d_in[17];
  const float* ln2b = (const float*)d_in[18];

  float* ws = (float*)d_ws;
  float* qkv = ws + OFF_QKV;
  float* att = ws + OFF_ATT;
  float* t_sorted = ws + OFF_TSORT;
  int* idx_sorted = (int*)(ws + OFF_IDX);
  float* dS = ws + OFF_DS;
  float* dC = ws + OFF_DC;
  float* S_tab = ws + OFF_STAB;
  float* C_tab = ws + OFF_CTAB;
  float* outp = (float*)d_out;

  hipLaunchKernelGGL(qkv_kernel, dim3(NROWS / 4), dim3(256), 0, stream, x,
                     Wqkv, bqkv, qkv);
  hipLaunchKernelGGL(sortdelta_kernel, dim3(1), dim3(1024), 0, stream, W1, b1,
                     W2, t_sorted, idx_sorted, dS, dC);
  hipLaunchKernelGGL(scan_kernel, dim3(DIMX), dim3(1024), 0, stream, W1, b1,
                     W2, b2, dS, dC, S_tab, C_tab);
  hipLaunchKernelGGL(attn_kernel, dim3(NROWS), dim3(256), 0, stream, pos, mask,
                     qkv, t_sorted, S_tab, C_tab, att);
  hipLaunchKernelGGL(tail_kernel, dim3(NROWS / 4), dim3(256), 0, stream, att,
                     x, Wo, bo, ln1g, ln1b, Wf1, bf1, Wf2, bf2, ln2g, ln2b,
                     outp);
}

// Round 2
// 164.566 us; speedup vs baseline: 2.2893x; 2.2893x over previous
//
#include <hip/hip_runtime.h>
#include <math.h>

#define NB 2
#define NN 192
#define DIMX 256
#define HID 1024
#define NROWS (NB * NN)            // 384
#define SCALING 0.17677669529663687f  // 1/sqrt(32)
#define EPS 1e-5f

// workspace layout (float offsets)
#define OFF_QKV   0
#define OFF_ATT   (OFF_QKV + NROWS * 768)        // 294912
#define OFF_TSORT (OFF_ATT + NROWS * DIMX)       // 393216
#define OFF_IDX   (OFF_TSORT + HID)              // 394240 (ints stored here)
#define OFF_STAB  (OFF_IDX + HID)                // 395264
#define OFF_CTAB  (OFF_STAB + (HID + 1) * DIMX)
// total = OFF_CTAB + (HID+1)*DIMX = 920,064 floats ≈ 3.7 MB

// ---------------- K1: qkv = x @ Wqkv + bqkv ----------------
// 1024 threads: (rr = tid>>8) row within the 4-row tile, (c = tid&255) col.
__global__ __launch_bounds__(1024) void qkv_kernel(
    const float* __restrict__ x, const float* __restrict__ Wqkv,
    const float* __restrict__ bqkv, float* __restrict__ qkv) {
  __shared__ float xs[4][DIMX];
  const int r0 = blockIdx.x * 4;
  const int tid = threadIdx.x;
  const int rr = tid >> 8;
  const int c = tid & 255;
  xs[rr][c] = x[(r0 + rr) * DIMX + c];
  __syncthreads();
  float a0 = 0.f, a1 = 0.f, a2 = 0.f;
  for (int k = 0; k < DIMX; ++k) {
    const float xv = xs[rr][k];
    a0 += xv * Wqkv[k * 768 + c];
    a1 += xv * Wqkv[k * 768 + 256 + c];
    a2 += xv * Wqkv[k * 768 + 512 + c];
  }
  const int row = r0 + rr;
  qkv[row * 768 + c] = a0 + bqkv[c];
  qkv[row * 768 + 256 + c] = a1 + bqkv[256 + c];
  qkv[row * 768 + 512 + c] = a2 + bqkv[512 + c];
}

// ------- K2: parallel rank-sort of PWL breakpoints -------
// 16 blocks; block bk ranks h in [bk*64, bk*64+64). Thread = (hl = tid>>4,
// chunk ck = tid&15); each thread counts over 64 r-values, LDS-reduce 16 ways.
__global__ __launch_bounds__(1024) void sortrank_kernel(
    const float* __restrict__ W1, const float* __restrict__ b1,
    float* __restrict__ t_sorted, int* __restrict__ idx_sorted) {
  __shared__ float ts[HID];
  __shared__ int part[64][17];
  const int tid = threadIdx.x;
  {
    const float w = W1[tid];
    ts[tid] = (w != 0.f) ? (-b1[tid] / w) : INFINITY;
  }
  __syncthreads();
  const int hl = tid >> 4;
  const int ck = tid & 15;
  const int h = blockIdx.x * 64 + hl;
  const float t = ts[h];
  int cnt = 0;
  const int r0 = ck * 64;
#pragma unroll 4
  for (int rr = 0; rr < 64; ++rr) {
    const int r = r0 + rr;
    const float tv = ts[r];
    cnt += ((tv < t) || (tv == t && r < h)) ? 1 : 0;
  }
  part[hl][ck] = cnt;
  __syncthreads();
  if (ck == 0) {
    int rank = 0;
#pragma unroll
    for (int u = 0; u < 16; ++u) rank += part[hl][u];
    t_sorted[rank] = t;
    idx_sorted[rank] = h;
  }
}

// ------- K3: baseline + inline deltas + inclusive scan -> S/C tables -------
__global__ __launch_bounds__(1024) void scan_kernel(
    const float* __restrict__ W1, const float* __restrict__ b1,
    const float* __restrict__ W2, const float* __restrict__ b2,
    const int* __restrict__ idx_sorted, float* __restrict__ S_tab,
    float* __restrict__ C_tab) {
  const int c = blockIdx.x;
  const int s = threadIdx.x;
  __shared__ float sS[HID];
  __shared__ float sC[HID];
  __shared__ float sW1[HID];
  __shared__ float sb1[HID];
  __shared__ int sidx[HID];
  sidx[s] = idx_sorted[s];
  const float w = W1[s];
  const float b1s = b1[s];
  sW1[s] = w;
  sb1[s] = b1s;
  // baseline: active set at d = -inf is {W1<0} plus constant {W1==0 && b1>0}
  {
    const float w2v = W2[s * DIMX + c];
    float bs = 0.f, bc = 0.f;
    if (w < 0.f) {
      bs = w * w2v;
      bc = b1s * w2v;
    } else if (w == 0.f && b1s > 0.f) {
      bc = b1s * w2v;
    }
    sS[s] = bs;
    sC[s] = bc;
  }
  __syncthreads();
  for (int off = 512; off > 0; off >>= 1) {
    if (s < off) {
      sS[s] += sS[s + off];
      sC[s] += sC[s + off];
    }
    __syncthreads();
  }
  const float S0 = sS[0];
  const float C0 = sC[0] + b2[c];
  __syncthreads();
  // per-segment delta (sorted order), computed inline
  float vS, vC;
  {
    const int hh = sidx[s];
    const float w1v = sW1[hh];
    const float sign = (w1v > 0.f) ? 1.f : -1.f;
    const float coefS = (w1v == 0.f) ? 0.f : sign * w1v;
    const float coefC = (w1v == 0.f) ? 0.f : sign * sb1[hh];
    const float w2v = W2[hh * DIMX + c];
    vS = coefS * w2v;
    vC = coefC * w2v;
  }
  sS[s] = vS;
  sC[s] = vC;
  __syncthreads();
  for (int off = 1; off < HID; off <<= 1) {
    float aS = 0.f, aC = 0.f;
    if (s >= off) {
      aS = sS[s - off];
      aC = sC[s - off];
    }
    __syncthreads();
    sS[s] += aS;
    sC[s] += aC;
    __syncthreads();
  }
  S_tab[(s + 1) * DIMX + c] = S0 + sS[s];
  C_tab[(s + 1) * DIMX + c] = C0 + sC[s];
  if (s == 0) {
    S_tab[c] = S0;
    C_tab[c] = C0;
  }
}

// ------- K4: fused distance-attention with per-channel online softmax -------
__global__ __launch_bounds__(256) void attn_kernel(
    const float* __restrict__ pos, const int* __restrict__ mask,
    const float* __restrict__ qkv, const float* __restrict__ t_sorted,
    const float* __restrict__ S_tab, const float* __restrict__ C_tab,
    float* __restrict__ att) {
  __shared__ float tS[HID];
  __shared__ float posB[NN][3];
  __shared__ int maskB[NN];
  __shared__ float dJ[NN];
  __shared__ float decJ[NN];
  __shared__ int segJ[NN];
  __shared__ int pmJ[NN];

  const int r = blockIdx.x;
  const int b = r / NN;
  const int i = r % NN;
  const int c = threadIdx.x;

  for (int u = c; u < HID; u += 256) tS[u] = t_sorted[u];
  for (int u = c; u < NN; u += 256) {
    posB[u][0] = pos[(b * NN + u) * 3 + 0];
    posB[u][1] = pos[(b * NN + u) * 3 + 1];
    posB[u][2] = pos[(b * NN + u) * 3 + 2];
    maskB[u] = mask[b * NN + u];
  }
  __syncthreads();

  if (c < NN) {
    const int j = c;
    const float dx = posB[j][0] - posB[i][0];
    const float dy = posB[j][1] - posB[i][1];
    const float dz = posB[j][2] - posB[i][2];
    const float sq = dx * dx + dy * dy + dz * dz;
    const float d = (sq > 0.f) ? sqrtf(sq) : 0.f;
    dJ[j] = d;
    decJ[j] = __expf(-sq * 0.1f);
    int lo = 0, hi = HID;
    while (lo < hi) {
      const int mid = (lo + hi) >> 1;
      if (tS[mid] <= d) lo = mid + 1;
      else hi = mid;
    }
    segJ[j] = lo;
    pmJ[j] = maskB[i] && maskB[j];
  }
  __syncthreads();

  const float kc = qkv[(b * NN + i) * 768 + 256 + c];
  float m = -3.0e38f, l = 0.f, o = 0.f;
  for (int j = 0; j < NN; ++j) {
    const int seg = segJ[j];
    const float de = C_tab[seg * DIMX + c] + dJ[j] * S_tab[seg * DIMX + c];
    const float qv = qkv[(b * NN + j) * 768 + c];
    const float vv = qkv[(b * NN + j) * 768 + 512 + c];
    float sval = decJ[j] * (kc + de) * (qv * SCALING);
    if (pmJ[j]) sval = -1e30f;
    const float mn = fmaxf(m, sval);
    const float rr = __expf(m - mn);
    const float p = __expf(sval - mn);
    l = l * rr + p;
    o = o * rr + p * vv;
    m = mn;
  }
  att[(b * NN + i) * DIMX + c] = o / l;
}

// ------- K5: out-proj + LN1 + FFN + LN2 -------
// 1024 threads: (rr = tid>>8) row of the 4-row tile, (c = tid&255) channel.
__device__ inline void rowReduce2(float v1, float v2, float (*red)[2],
                                  float* o1, float* o2) {
  for (int off = 32; off > 0; off >>= 1) {
    v1 += __shfl_down(v1, off);
    v2 += __shfl_down(v2, off);
  }
  const int w = threadIdx.x >> 6;
  if ((threadIdx.x & 63) == 0) {
    red[w][0] = v1;
    red[w][1] = v2;
  }
  __syncthreads();
  const int base = (threadIdx.x >> 8) << 2;
  *o1 = red[base][0] + red[base + 1][0] + red[base + 2][0] + red[base + 3][0];
  *o2 = red[base][1] + red[base + 1][1] + red[base + 2][1] + red[base + 3][1];
  __syncthreads();
}

__global__ __launch_bounds__(1024) void tail_kernel(
    const float* __restrict__ att, const float* __restrict__ x,
    const float* __restrict__ Wo, const float* __restrict__ bo,
    const float* __restrict__ ln1g, const float* __restrict__ ln1b,
    const float* __restrict__ Wf1, const float* __restrict__ bf1,
    const float* __restrict__ Wf2, const float* __restrict__ bf2,
    const float* __restrict__ ln2g, const float* __restrict__ ln2b,
    float* __restrict__ out) {
  __shared__ float atts[4][DIMX];
  __shared__ float x1s[4][DIMX];
  __shared__ float hids[4][HID];
  __shared__ float red[16][2];
  const int r0 = blockIdx.x * 4;
  const int tid = threadIdx.x;
  const int rr = tid >> 8;
  const int c = tid & 255;
  const int row = r0 + rr;

  atts[rr][c] = att[row * DIMX + c];
  const float xr = x[row * DIMX + c];
  __syncthreads();

  float a = 0.f;
  for (int k = 0; k < DIMX; ++k) a += atts[rr][k] * Wo[k * DIMX + c];
  const float t1 = xr + a + bo[c];

  float s1, s2;
  rowReduce2(t1, t1 * t1, red, &s1, &s2);
  {
    const float mu = s1 * (1.f / DIMX);
    const float var = s2 * (1.f / DIMX) - mu * mu;
    x1s[rr][c] = (t1 - mu) * rsqrtf(var + EPS) * ln1g[c] + ln1b[c];
  }
  __syncthreads();

  float h0 = 0.f, h1 = 0.f, h2 = 0.f, h3 = 0.f;
  for (int k = 0; k < DIMX; ++k) {
    const float xv = x1s[rr][k];
    h0 += xv * Wf1[k * HID + c];
    h1 += xv * Wf1[k * HID + 256 + c];
    h2 += xv * Wf1[k * HID + 512 + c];
    h3 += xv * Wf1[k * HID + 768 + c];
  }
  hids[rr][c] = fmaxf(h0 + bf1[c], 0.f);
  hids[rr][256 + c] = fmaxf(h1 + bf1[256 + c], 0.f);
  hids[rr][512 + c] = fmaxf(h2 + bf1[512 + c], 0.f);
  hids[rr][768 + c] = fmaxf(h3 + bf1[768 + c], 0.f);
  __syncthreads();

  float o2 = 0.f;
  for (int t = 0; t < HID; ++t) o2 += hids[rr][t] * Wf2[t * DIMX + c];
  const float t2 = x1s[rr][c] + o2 + bf2[c];
  rowReduce2(t2, t2 * t2, red, &s1, &s2);
  {
    const float mu = s1 * (1.f / DIMX);
    const float var = s2 * (1.f / DIMX) - mu * mu;
    out[row * DIMX + c] = (t2 - mu) * rsqrtf(var + EPS) * ln2g[c] + ln2b[c];
  }
}

extern "C" void kernel_launch(void* const* d_in, const int* in_sizes, int n_in,
                              void* d_out, int out_size, void* d_ws,
                              size_t ws_size, hipStream_t stream) {
  const float* x = (const float*)d_in[0];
  const float* pos = (const float*)d_in[1];
  const int* mask = (const int*)d_in[2];
  const float* Wqkv = (const float*)d_in[3];
  const float* bqkv = (const float*)d_in[4];
  const float* W1 = (const float*)d_in[5];
  const float* b1 = (const float*)d_in[6];
  const float* W2 = (const float*)d_in[7];
  const float* b2 = (const float*)d_in[8];
  const float* Wo = (const float*)d_in[9];
  const float* bo = (const float*)d_in[10];
  const float* ln1g = (const float*)d_in[11];
  const float* ln1b = (const float*)d_in[12];
  const float* Wf1 = (const float*)d_in[13];
  const float* bf1 = (const float*)d_in[14];
  const float* Wf2 = (const float*)d_in[15];
  const float* bf2 = (const float*)d_in[16];
  const float* ln2g = (const float*)d_in[17];
  const float* ln2b = (const float*)d_in[18];

  float* ws = (float*)d_ws;
  float* qkv = ws + OFF_QKV;
  float* att = ws + OFF_ATT;
  float* t_sorted = ws + OFF_TSORT;
  int* idx_sorted = (int*)(ws + OFF_IDX);
  float* S_tab = ws + OFF_STAB;
  float* C_tab = ws + OFF_CTAB;
  float* outp = (float*)d_out;

  hipLaunchKernelGGL(qkv_kernel, dim3(NROWS / 4), dim3(1024), 0, stream, x,
                     Wqkv, bqkv, qkv);
  hipLaunchKernelGGL(sortrank_kernel, dim3(16), dim3(1024), 0, stream, W1, b1,
                     t_sorted, idx_sorted);
  hipLaunchKernelGGL(scan_kernel, dim3(DIMX), dim3(1024), 0, stream, W1, b1,
                     W2, b2, idx_sorted, S_tab, C_tab);
  hipLaunchKernelGGL(attn_kernel, dim3(NROWS), dim3(256), 0, stream, pos, mask,
                     qkv, t_sorted, S_tab, C_tab, att);
  hipLaunchKernelGGL(tail_kernel, dim3(NROWS / 4), dim3(1024), 0, stream, att,
                     x, Wo, bo, ln1g, ln1b, Wf1, bf1, Wf2, bf2, ln2g, ln2b,
                     outp);
}

// Round 3
// 152.119 us; speedup vs baseline: 2.4766x; 1.0818x over previous
//
#include <hip/hip_runtime.h>
#include <math.h>

#define NB 2
#define NN 192
#define DIMX 256
#define HID 1024
#define NROWS (NB * NN)            // 384
#define SCALING 0.17677669529663687f  // 1/sqrt(32)
#define EPS 1e-5f

// workspace layout (float offsets)
#define OFF_QKV   0
#define OFF_ATT   (OFF_QKV + NROWS * 768)        // 294912
#define OFF_TSORT (OFF_ATT + NROWS * DIMX)       // 393216
#define OFF_IDX   (OFF_TSORT + HID)              // 394240 (ints)
#define OFF_STAB  (OFF_IDX + HID)                // 395264
#define OFF_CTAB  (OFF_STAB + (HID + 1) * DIMX)  // 657664
#define OFF_X1    (OFF_CTAB + (HID + 1) * DIMX)  // 920064
#define OFF_HIDB  (OFF_X1 + NROWS * DIMX)        // 1018368
// end = OFF_HIDB + NROWS*HID = 1,411,584 floats ≈ 5.65 MB (< R0's 5.78 MB)

// ---------------- K1: qkv = x @ Wqkv + bqkv ----------------
// 192 blocks, 2 rows each; tid -> (kc = tid>>9, rr = (tid>>8)&1, c = tid&255)
__global__ __launch_bounds__(1024) void qkv_kernel(
    const float* __restrict__ x, const float* __restrict__ Wqkv,
    const float* __restrict__ bqkv, float* __restrict__ qkv) {
  __shared__ float xs[2][DIMX];
  __shared__ float red[2][2][768];  // [kc][rr][768] = 12 KB
  const int r0 = blockIdx.x * 2;
  const int tid = threadIdx.x;
  const int c = tid & 255;
  const int rr = (tid >> 8) & 1;
  const int kc = tid >> 9;
  if (tid < 512) xs[tid >> 8][tid & 255] = x[(r0 + (tid >> 8)) * DIMX + (tid & 255)];
  __syncthreads();
  float a0 = 0.f, a1 = 0.f, a2 = 0.f;
  const int k0 = kc * 128;
#pragma unroll 4
  for (int i = 0; i < 128; ++i) {
    const int k = k0 + i;
    const float xv = xs[rr][k];
    a0 += xv * Wqkv[k * 768 + c];
    a1 += xv * Wqkv[k * 768 + 256 + c];
    a2 += xv * Wqkv[k * 768 + 512 + c];
  }
  red[kc][rr][c] = a0;
  red[kc][rr][256 + c] = a1;
  red[kc][rr][512 + c] = a2;
  __syncthreads();
  if (kc == 0) {
    const int row = r0 + rr;
    qkv[row * 768 + c] = red[0][rr][c] + red[1][rr][c] + bqkv[c];
    qkv[row * 768 + 256 + c] = red[0][rr][256 + c] + red[1][rr][256 + c] + bqkv[256 + c];
    qkv[row * 768 + 512 + c] = red[0][rr][512 + c] + red[1][rr][512 + c] + bqkv[512 + c];
  }
}

// ------- K2: parallel rank-sort of PWL breakpoints -------
__global__ __launch_bounds__(1024) void sortrank_kernel(
    const float* __restrict__ W1, const float* __restrict__ b1,
    float* __restrict__ t_sorted, int* __restrict__ idx_sorted) {
  __shared__ float ts[HID];
  __shared__ int part[64][17];
  const int tid = threadIdx.x;
  {
    const float w = W1[tid];
    ts[tid] = (w != 0.f) ? (-b1[tid] / w) : INFINITY;
  }
  __syncthreads();
  const int hl = tid >> 4;
  const int ck = tid & 15;
  const int h = blockIdx.x * 64 + hl;
  const float t = ts[h];
  int cnt = 0;
  const int r0 = ck * 64;
#pragma unroll 4
  for (int rr = 0; rr < 64; ++rr) {
    const int r = r0 + rr;
    const float tv = ts[r];
    cnt += ((tv < t) || (tv == t && r < h)) ? 1 : 0;
  }
  part[hl][ck] = cnt;
  __syncthreads();
  if (ck == 0) {
    int rank = 0;
#pragma unroll
    for (int u = 0; u < 16; ++u) rank += part[hl][u];
    t_sorted[rank] = t;
    idx_sorted[rank] = h;
  }
}

// ------- K3: baseline + inline deltas + inclusive scan -> S/C tables -------
__global__ __launch_bounds__(1024) void scan_kernel(
    const float* __restrict__ W1, const float* __restrict__ b1,
    const float* __restrict__ W2, const float* __restrict__ b2,
    const int* __restrict__ idx_sorted, float* __restrict__ S_tab,
    float* __restrict__ C_tab) {
  const int c = blockIdx.x;
  const int s = threadIdx.x;
  __shared__ float sS[HID];
  __shared__ float sC[HID];
  __shared__ float sW1[HID];
  __shared__ float sb1[HID];
  __shared__ int sidx[HID];
  sidx[s] = idx_sorted[s];
  const float w = W1[s];
  const float b1s = b1[s];
  sW1[s] = w;
  sb1[s] = b1s;
  {
    const float w2v = W2[s * DIMX + c];
    float bs = 0.f, bc = 0.f;
    if (w < 0.f) {
      bs = w * w2v;
      bc = b1s * w2v;
    } else if (w == 0.f && b1s > 0.f) {
      bc = b1s * w2v;
    }
    sS[s] = bs;
    sC[s] = bc;
  }
  __syncthreads();
  for (int off = 512; off > 0; off >>= 1) {
    if (s < off) {
      sS[s] += sS[s + off];
      sC[s] += sC[s + off];
    }
    __syncthreads();
  }
  const float S0 = sS[0];
  const float C0 = sC[0] + b2[c];
  __syncthreads();
  float vS, vC;
  {
    const int hh = sidx[s];
    const float w1v = sW1[hh];
    const float sign = (w1v > 0.f) ? 1.f : -1.f;
    const float coefS = (w1v == 0.f) ? 0.f : sign * w1v;
    const float coefC = (w1v == 0.f) ? 0.f : sign * sb1[hh];
    const float w2v = W2[hh * DIMX + c];
    vS = coefS * w2v;
    vC = coefC * w2v;
  }
  sS[s] = vS;
  sC[s] = vC;
  __syncthreads();
  for (int off = 1; off < HID; off <<= 1) {
    float aS = 0.f, aC = 0.f;
    if (s >= off) {
      aS = sS[s - off];
      aC = sC[s - off];
    }
    __syncthreads();
    sS[s] += aS;
    sC[s] += aC;
    __syncthreads();
  }
  S_tab[(s + 1) * DIMX + c] = S0 + sS[s];
  C_tab[(s + 1) * DIMX + c] = C0 + sC[s];
  if (s == 0) {
    S_tab[c] = S0;
    C_tab[c] = C0;
  }
}

// ------- K4: fused distance-attention, 4-way j-split, no-max softmax -------
// |sval| is tiny (decay<=1, k/q/de ~ +-0.5) so exp never overflows; masked
// entries exp(-1e30)->0 exactly. All-masked rows cannot occur (ref would NaN).
__global__ __launch_bounds__(1024) void attn_kernel(
    const float* __restrict__ pos, const int* __restrict__ mask,
    const float* __restrict__ qkv, const float* __restrict__ t_sorted,
    const float* __restrict__ S_tab, const float* __restrict__ C_tab,
    float* __restrict__ att) {
  __shared__ float tS[HID];
  __shared__ float posB[NN][3];
  __shared__ int maskB[NN];
  __shared__ float dJ[NN];
  __shared__ float decJ[NN];
  __shared__ int segJ[NN];
  __shared__ int pmJ[NN];
  __shared__ float sl[4][DIMX];
  __shared__ float so[4][DIMX];

  const int r = blockIdx.x;
  const int b = r / NN;
  const int i = r % NN;
  const int tid = threadIdx.x;
  const int c = tid & 255;
  const int jq = tid >> 8;

  tS[tid] = t_sorted[tid];
  if (tid < NN) {
    posB[tid][0] = pos[(b * NN + tid) * 3 + 0];
    posB[tid][1] = pos[(b * NN + tid) * 3 + 1];
    posB[tid][2] = pos[(b * NN + tid) * 3 + 2];
    maskB[tid] = mask[b * NN + tid];
  }
  __syncthreads();

  if (tid < NN) {
    const int j = tid;
    const float dx = posB[j][0] - posB[i][0];
    const float dy = posB[j][1] - posB[i][1];
    const float dz = posB[j][2] - posB[i][2];
    const float sq = dx * dx + dy * dy + dz * dz;
    const float d = (sq > 0.f) ? sqrtf(sq) : 0.f;
    dJ[j] = d;
    decJ[j] = __expf(-sq * 0.1f);
    int lo = 0, hi = HID;
    while (lo < hi) {
      const int mid = (lo + hi) >> 1;
      if (tS[mid] <= d) lo = mid + 1;
      else hi = mid;
    }
    segJ[j] = lo;
    pmJ[j] = maskB[i] && maskB[j];
  }
  __syncthreads();

  const float kc_ = qkv[(b * NN + i) * 768 + 256 + c];
  float l = 0.f, o = 0.f;
  const int j0 = jq * 48;
#pragma unroll 2
  for (int jj = 0; jj < 48; ++jj) {
    const int j = j0 + jj;
    const int seg = segJ[j];
    const float de = C_tab[seg * DIMX + c] + dJ[j] * S_tab[seg * DIMX + c];
    const float qv = qkv[(b * NN + j) * 768 + c];
    const float vv = qkv[(b * NN + j) * 768 + 512 + c];
    const float sval = decJ[j] * (kc_ + de) * (qv * SCALING);
    const float p = pmJ[j] ? 0.f : __expf(sval);
    l += p;
    o += p * vv;
  }
  sl[jq][c] = l;
  so[jq][c] = o;
  __syncthreads();
  if (tid < DIMX) {
    const float lt = sl[0][tid] + sl[1][tid] + sl[2][tid] + sl[3][tid];
    const float ot = so[0][tid] + so[1][tid] + so[2][tid] + so[3][tid];
    att[r * DIMX + tid] = ot / lt;
  }
}

// ------- K5a: out-proj + LN1 (2 rows/block, 16-way k-split, float4) -------
__global__ __launch_bounds__(1024) void proj_ln1_kernel(
    const float* __restrict__ att, const float* __restrict__ x,
    const float* __restrict__ Wo, const float* __restrict__ bo,
    const float* __restrict__ ln1g, const float* __restrict__ ln1b,
    float* __restrict__ x1) {
  __shared__ float atts[2][DIMX];
  __shared__ float4 red[16][2][64];  // 32 KB
  __shared__ float lr1[16], lr2[16];
  const int r0 = blockIdx.x * 2;
  const int tid = threadIdx.x;
  const int kc = tid >> 6;
  const int c4 = tid & 63;
  if (tid < 512) atts[tid >> 8][tid & 255] = att[(r0 + (tid >> 8)) * DIMX + (tid & 255)];
  __syncthreads();
  float4 a0 = {0.f, 0.f, 0.f, 0.f}, a1 = {0.f, 0.f, 0.f, 0.f};
  const float4* Wo4 = (const float4*)Wo;
#pragma unroll
  for (int i = 0; i < 16; ++i) {
    const int k = kc * 16 + i;
    const float4 w = Wo4[k * 64 + c4];
    const float v0 = atts[0][k], v1 = atts[1][k];
    a0.x += v0 * w.x; a0.y += v0 * w.y; a0.z += v0 * w.z; a0.w += v0 * w.w;
    a1.x += v1 * w.x; a1.y += v1 * w.y; a1.z += v1 * w.z; a1.w += v1 * w.w;
  }
  red[kc][0][c4] = a0;
  red[kc][1][c4] = a1;
  __syncthreads();
  for (int off = 8; off > 0; off >>= 1) {
    if (kc < off) {
      float4 p = red[kc][0][c4], q = red[kc + off][0][c4];
      p.x += q.x; p.y += q.y; p.z += q.z; p.w += q.w;
      red[kc][0][c4] = p;
      float4 p1 = red[kc][1][c4], q1 = red[kc + off][1][c4];
      p1.x += q1.x; p1.y += q1.y; p1.z += q1.z; p1.w += q1.w;
      red[kc][1][c4] = p1;
    }
    __syncthreads();
  }
  const int rr = tid >> 8;  // 0..3
  const int c = tid & 255;
  float t1 = 0.f;
  if (rr < 2) {
    const float4 v = red[0][rr][c >> 2];
    const float pv = ((const float*)&v)[c & 3];
    t1 = pv + x[(r0 + rr) * DIMX + c] + bo[c];
  }
  float s1 = t1, s2 = t1 * t1;
  for (int off = 32; off > 0; off >>= 1) {
    s1 += __shfl_down(s1, off);
    s2 += __shfl_down(s2, off);
  }
  const int wv = tid >> 6;
  if ((tid & 63) == 0) { lr1[wv] = s1; lr2[wv] = s2; }
  __syncthreads();
  if (rr < 2) {
    const int base = rr * 4;
    const float S1 = lr1[base] + lr1[base + 1] + lr1[base + 2] + lr1[base + 3];
    const float S2 = lr2[base] + lr2[base + 1] + lr2[base + 2] + lr2[base + 3];
    const float mu = S1 * (1.f / DIMX);
    const float var = S2 * (1.f / DIMX) - mu * mu;
    x1[(r0 + rr) * DIMX + c] = (t1 - mu) * rsqrtf(var + EPS) * ln1g[c] + ln1b[c];
  }
}

// ------- K5b: FFN1 = relu(x1 @ Wf1 + bf1) (2 rows/block) -------
__global__ __launch_bounds__(1024) void ffn1_kernel(
    const float* __restrict__ x1, const float* __restrict__ Wf1,
    const float* __restrict__ bf1, float* __restrict__ hid) {
  __shared__ float x1s[2][DIMX];
  const int r0 = blockIdx.x * 2;
  const int tid = threadIdx.x;
  if (tid < 512) x1s[tid >> 8][tid & 255] = x1[(r0 + (tid >> 8)) * DIMX + (tid & 255)];
  __syncthreads();
  float a0 = 0.f, a1 = 0.f;
#pragma unroll 4
  for (int k = 0; k < DIMX; ++k) {
    const float w = Wf1[k * HID + tid];
    a0 += x1s[0][k] * w;
    a1 += x1s[1][k] * w;
  }
  const float b = bf1[tid];
  hid[r0 * HID + tid] = fmaxf(a0 + b, 0.f);
  hid[(r0 + 1) * HID + tid] = fmaxf(a1 + b, 0.f);
}

// ------- K5c: FFN2 + LN2 (2 rows/block, 16-way k-split, float4) -------
__global__ __launch_bounds__(1024) void ffn2_ln2_kernel(
    const float* __restrict__ hid, const float* __restrict__ x1,
    const float* __restrict__ Wf2, const float* __restrict__ bf2,
    const float* __restrict__ ln2g, const float* __restrict__ ln2b,
    float* __restrict__ out) {
  __shared__ float hs[2][HID];       // 8 KB
  __shared__ float4 red[16][2][64];  // 32 KB
  __shared__ float lr1[16], lr2[16];
  const int r0 = blockIdx.x * 2;
  const int tid = threadIdx.x;
  const int kc = tid >> 6;
  const int c4 = tid & 63;
  ((float*)hs)[tid] = hid[r0 * HID + tid];
  ((float*)hs)[tid + 1024] = hid[r0 * HID + tid + 1024];
  __syncthreads();
  float4 a0 = {0.f, 0.f, 0.f, 0.f}, a1 = {0.f, 0.f, 0.f, 0.f};
  const float4* W4 = (const float4*)Wf2;
#pragma unroll 4
  for (int i = 0; i < 64; ++i) {
    const int k = kc * 64 + i;
    const float4 w = W4[k * 64 + c4];
    const float h0 = hs[0][k], h1 = hs[1][k];
    a0.x += h0 * w.x; a0.y += h0 * w.y; a0.z += h0 * w.z; a0.w += h0 * w.w;
    a1.x += h1 * w.x; a1.y += h1 * w.y; a1.z += h1 * w.z; a1.w += h1 * w.w;
  }
  red[kc][0][c4] = a0;
  red[kc][1][c4] = a1;
  __syncthreads();
  for (int off = 8; off > 0; off >>= 1) {
    if (kc < off) {
      float4 p = red[kc][0][c4], q = red[kc + off][0][c4];
      p.x += q.x; p.y += q.y; p.z += q.z; p.w += q.w;
      red[kc][0][c4] = p;
      float4 p1 = red[kc][1][c4], q1 = red[kc + off][1][c4];
      p1.x += q1.x; p1.y += q1.y; p1.z += q1.z; p1.w += q1.w;
      red[kc][1][c4] = p1;
    }
    __syncthreads();
  }
  const int rr = tid >> 8;
  const int c = tid & 255;
  float t2 = 0.f;
  if (rr < 2) {
    const float4 v = red[0][rr][c >> 2];
    const float pv = ((const float*)&v)[c & 3];
    t2 = pv + x1[(r0 + rr) * DIMX + c] + bf2[c];
  }
  float s1 = t2, s2 = t2 * t2;
  for (int off = 32; off > 0; off >>= 1) {
    s1 += __shfl_down(s1, off);
    s2 += __shfl_down(s2, off);
  }
  const int wv = tid >> 6;
  if ((tid & 63) == 0) { lr1[wv] = s1; lr2[wv] = s2; }
  __syncthreads();
  if (rr < 2) {
    const int base = rr * 4;
    const float S1 = lr1[base] + lr1[base + 1] + lr1[base + 2] + lr1[base + 3];
    const float S2 = lr2[base] + lr2[base + 1] + lr2[base + 2] + lr2[base + 3];
    const float mu = S1 * (1.f / DIMX);
    const float var = S2 * (1.f / DIMX) - mu * mu;
    out[(r0 + rr) * DIMX + c] = (t2 - mu) * rsqrtf(var + EPS) * ln2g[c] + ln2b[c];
  }
}

extern "C" void kernel_launch(void* const* d_in, const int* in_sizes, int n_in,
                              void* d_out, int out_size, void* d_ws,
                              size_t ws_size, hipStream_t stream) {
  const float* x = (const float*)d_in[0];
  const float* pos = (const float*)d_in[1];
  const int* mask = (const int*)d_in[2];
  const float* Wqkv = (const float*)d_in[3];
  const float* bqkv = (const float*)d_in[4];
  const float* W1 = (const float*)d_in[5];
  const float* b1 = (const float*)d_in[6];
  const float* W2 = (const float*)d_in[7];
  const float* b2 = (const float*)d_in[8];
  const float* Wo = (const float*)d_in[9];
  const float* bo = (const float*)d_in[10];
  const float* ln1g = (const float*)d_in[11];
  const float* ln1b = (const float*)d_in[12];
  const float* Wf1 = (const float*)d_in[13];
  const float* bf1 = (const float*)d_in[14];
  const float* Wf2 = (const float*)d_in[15];
  const float* bf2 = (const float*)d_in[16];
  const float* ln2g = (const float*)d_in[17];
  const float* ln2b = (const float*)d_in[18];

  float* ws = (float*)d_ws;
  float* qkv = ws + OFF_QKV;
  float* att = ws + OFF_ATT;
  float* t_sorted = ws + OFF_TSORT;
  int* idx_sorted = (int*)(ws + OFF_IDX);
  float* S_tab = ws + OFF_STAB;
  float* C_tab = ws + OFF_CTAB;
  float* x1 = ws + OFF_X1;
  float* hid = ws + OFF_HIDB;
  float* outp = (float*)d_out;

  hipLaunchKernelGGL(qkv_kernel, dim3(NROWS / 2), dim3(1024), 0, stream, x,
                     Wqkv, bqkv, qkv);
  hipLaunchKernelGGL(sortrank_kernel, dim3(16), dim3(1024), 0, stream, W1, b1,
                     t_sorted, idx_sorted);
  hipLaunchKernelGGL(scan_kernel, dim3(DIMX), dim3(1024), 0, stream, W1, b1,
                     W2, b2, idx_sorted, S_tab, C_tab);
  hipLaunchKernelGGL(attn_kernel, dim3(NROWS), dim3(1024), 0, stream, pos,
                     mask, qkv, t_sorted, S_tab, C_tab, att);
  hipLaunchKernelGGL(proj_ln1_kernel, dim3(NROWS / 2), dim3(1024), 0, stream,
                     att, x, Wo, bo, ln1g, ln1b, x1);
  hipLaunchKernelGGL(ffn1_kernel, dim3(NROWS / 2), dim3(1024), 0, stream, x1,
                     Wf1, bf1, hid);
  hipLaunchKernelGGL(ffn2_ln2_kernel, dim3(NROWS / 2), dim3(1024), 0, stream,
                     hid, x1, Wf2, bf2, ln2g, ln2b, outp);
}

// Round 4
// 111.007 us; speedup vs baseline: 3.3938x; 1.3704x over previous
//
#include <hip/hip_runtime.h>
#include <math.h>

#define NB 2
#define NN 192
#define DIMX 256
#define HID 1024
#define NROWS (NB * NN)            // 384
#define SCALING 0.17677669529663687f  // 1/sqrt(32)
#define EPS 1e-5f

// workspace layout (float offsets)
#define OFF_KK    0                              // k-part, NROWS*256
#define OFF_QV    (OFF_KK + NROWS * DIMX)        // float2 q,v  NROWS*256*2
#define OFF_TSORT (OFF_QV + NROWS * DIMX * 2)    // 1024
#define OFF_IDX   (OFF_TSORT + HID)              // 1024 ints
#define OFF_SC    (OFF_IDX + HID)                // float2 (HID+1)*256*2
#define OFF_ATT   (OFF_SC + (HID + 1) * DIMX * 2)
// end = OFF_ATT + NROWS*DIMX = 920,064 floats ≈ 3.7 MB

// ---------------- K1: prep = qkv GEMM (blocks 0..191) + sortrank (192..207)
__global__ __launch_bounds__(1024) void prep_kernel(
    const float* __restrict__ x, const float* __restrict__ Wqkv,
    const float* __restrict__ bqkv, const float* __restrict__ W1,
    const float* __restrict__ b1, float* __restrict__ kk,
    float2* __restrict__ qv2, float* __restrict__ t_sorted,
    int* __restrict__ idx_sorted) {
  __shared__ float xs[2][DIMX];
  __shared__ float red[2][2][768];  // 12 KB
  __shared__ float ts[HID];
  __shared__ int part[64][17];
  const int tid = threadIdx.x;
  if (blockIdx.x < 192) {
    const int r0 = blockIdx.x * 2;
    const int c = tid & 255;
    const int rr = (tid >> 8) & 1;
    const int kc = tid >> 9;
    if (tid < 512)
      xs[tid >> 8][tid & 255] = x[(r0 + (tid >> 8)) * DIMX + (tid & 255)];
    __syncthreads();
    float a0 = 0.f, a1 = 0.f, a2 = 0.f;
    const int k0 = kc * 128;
#pragma unroll 4
    for (int i = 0; i < 128; ++i) {
      const int k = k0 + i;
      const float xv = xs[rr][k];
      a0 += xv * Wqkv[k * 768 + c];
      a1 += xv * Wqkv[k * 768 + 256 + c];
      a2 += xv * Wqkv[k * 768 + 512 + c];
    }
    red[kc][rr][c] = a0;
    red[kc][rr][256 + c] = a1;
    red[kc][rr][512 + c] = a2;
    __syncthreads();
    if (kc == 0) {
      const int row = r0 + rr;
      kk[row * DIMX + c] = red[0][rr][256 + c] + red[1][rr][256 + c] + bqkv[256 + c];
      const float q = red[0][rr][c] + red[1][rr][c] + bqkv[c];
      const float v = red[0][rr][512 + c] + red[1][rr][512 + c] + bqkv[512 + c];
      qv2[row * DIMX + c] = make_float2(q, v);
    }
  } else {
    const int bk = blockIdx.x - 192;
    {
      const float w = W1[tid];
      ts[tid] = (w != 0.f) ? (-b1[tid] / w) : INFINITY;
    }
    __syncthreads();
    const int hl = tid >> 4;
    const int ck = tid & 15;
    const int h = bk * 64 + hl;
    const float t = ts[h];
    int cnt = 0;
    const int r0 = ck * 64;
#pragma unroll 4
    for (int rr = 0; rr < 64; ++rr) {
      const int r = r0 + rr;
      const float tv = ts[r];
      cnt += ((tv < t) || (tv == t && r < h)) ? 1 : 0;
    }
    part[hl][ck] = cnt;
    __syncthreads();
    if (ck == 0) {
      int rank = 0;
#pragma unroll
      for (int u = 0; u < 16; ++u) rank += part[hl][u];
      t_sorted[rank] = t;
      idx_sorted[rank] = h;
    }
  }
}

// ------- K2: baseline + deltas + wave-shuffle inclusive scan -> SC table ----
__global__ __launch_bounds__(1024) void scan_kernel(
    const float* __restrict__ W1, const float* __restrict__ b1,
    const float* __restrict__ W2, const float* __restrict__ b2,
    const int* __restrict__ idx_sorted, float2* __restrict__ SC) {
  const int c = blockIdx.x;
  const int tid = threadIdx.x;
  const int lane = tid & 63;
  const int wid = tid >> 6;
  __shared__ float sW1[HID];
  __shared__ float sb1[HID];
  __shared__ int sidx[HID];
  __shared__ float bws[16], bwc[16], tws[16], twc[16];

  const float w = W1[tid];
  const float b1s = b1[tid];
  sW1[tid] = w;
  sb1[tid] = b1s;
  sidx[tid] = idx_sorted[tid];

  // baseline contribution (active set at d = -inf)
  float bs = 0.f, bc = 0.f;
  {
    const float w2v = W2[tid * DIMX + c];
    if (w < 0.f) {
      bs = w * w2v;
      bc = b1s * w2v;
    } else if (w == 0.f && b1s > 0.f) {
      bc = b1s * w2v;
    }
  }
  for (int off = 32; off > 0; off >>= 1) {
    bs += __shfl_down(bs, off);
    bc += __shfl_down(bc, off);
  }
  __syncthreads();  // sW1/sb1/sidx ready

  // per-segment delta (sorted order s = tid)
  float vS, vC;
  {
    const int hh = sidx[tid];
    const float w1v = sW1[hh];
    const float sign = (w1v > 0.f) ? 1.f : -1.f;
    const float coefS = (w1v == 0.f) ? 0.f : sign * w1v;
    const float coefC = (w1v == 0.f) ? 0.f : sign * sb1[hh];
    const float w2v = W2[hh * DIMX + c];
    vS = coefS * w2v;
    vC = coefC * w2v;
  }
  // wave-inclusive scan
  for (int off = 1; off < 64; off <<= 1) {
    const float tS_ = __shfl_up(vS, off);
    const float tC_ = __shfl_up(vC, off);
    if (lane >= off) {
      vS += tS_;
      vC += tC_;
    }
  }
  if (lane == 0) {
    bws[wid] = bs;
    bwc[wid] = bc;
  }
  if (lane == 63) {
    tws[wid] = vS;
    twc[wid] = vC;
  }
  __syncthreads();
  float S0 = 0.f, C0 = 0.f, offS = 0.f, offC = 0.f;
#pragma unroll
  for (int u = 0; u < 16; ++u) {
    S0 += bws[u];
    C0 += bwc[u];
    if (u < wid) {
      offS += tws[u];
      offC += twc[u];
    }
  }
  C0 += b2[c];
  SC[(tid + 1) * DIMX + c] = make_float2(S0 + offS + vS, C0 + offC + vC);
  if (tid == 0) SC[c] = make_float2(S0, C0);
}

// ------- K3: fused distance-attention, 4-way j-split, no-max softmax -------
__global__ __launch_bounds__(1024) void attn_kernel(
    const float* __restrict__ pos, const int* __restrict__ mask,
    const float* __restrict__ kk, const float2* __restrict__ qv2,
    const float* __restrict__ t_sorted, const float2* __restrict__ SC,
    float* __restrict__ att) {
  __shared__ float tS[HID];
  __shared__ float posB[NN][3];
  __shared__ int maskB[NN];
  __shared__ float dJ[NN];
  __shared__ float decJ[NN];
  __shared__ int segJ[NN];
  __shared__ int pmJ[NN];
  __shared__ float sl[4][DIMX];
  __shared__ float so[4][DIMX];

  const int r = blockIdx.x;
  const int b = r / NN;
  const int i = r % NN;
  const int tid = threadIdx.x;
  const int c = tid & 255;
  const int jq = tid >> 8;

  tS[tid] = t_sorted[tid];
  if (tid < NN) {
    posB[tid][0] = pos[(b * NN + tid) * 3 + 0];
    posB[tid][1] = pos[(b * NN + tid) * 3 + 1];
    posB[tid][2] = pos[(b * NN + tid) * 3 + 2];
    maskB[tid] = mask[b * NN + tid];
  }
  __syncthreads();

  if (tid < NN) {
    const int j = tid;
    const float dx = posB[j][0] - posB[i][0];
    const float dy = posB[j][1] - posB[i][1];
    const float dz = posB[j][2] - posB[i][2];
    const float sq = dx * dx + dy * dy + dz * dz;
    const float d = (sq > 0.f) ? sqrtf(sq) : 0.f;
    dJ[j] = d;
    decJ[j] = __expf(-sq * 0.1f);
    int lo = 0, hi = HID;
    while (lo < hi) {
      const int mid = (lo + hi) >> 1;
      if (tS[mid] <= d) lo = mid + 1;
      else hi = mid;
    }
    segJ[j] = lo;
    pmJ[j] = maskB[i] && maskB[j];
  }
  __syncthreads();

  const float kc_ = kk[(b * NN + i) * DIMX + c];
  float l = 0.f, o = 0.f;
  const int j0 = jq * 48;
#pragma unroll 2
  for (int jj = 0; jj < 48; ++jj) {
    const int j = j0 + jj;
    const int seg = segJ[j];
    const float2 sc = SC[seg * DIMX + c];
    const float de = sc.y + dJ[j] * sc.x;
    const float2 qv = qv2[(b * NN + j) * DIMX + c];
    const float sval = decJ[j] * (kc_ + de) * (qv.x * SCALING);
    const float p = pmJ[j] ? 0.f : __expf(sval);
    l += p;
    o += p * qv.y;
  }
  sl[jq][c] = l;
  so[jq][c] = o;
  __syncthreads();
  if (tid < DIMX) {
    const float lt = sl[0][tid] + sl[1][tid] + sl[2][tid] + sl[3][tid];
    const float ot = so[0][tid] + so[1][tid] + so[2][tid] + so[3][tid];
    att[r * DIMX + tid] = ot / lt;
  }
}

// ------- K4: fused tail: proj + LN1 + FFN1 + FFN2 + LN2 (2 rows/block) -----
__global__ __launch_bounds__(1024) void tail_kernel(
    const float* __restrict__ att, const float* __restrict__ x,
    const float* __restrict__ Wo, const float* __restrict__ bo,
    const float* __restrict__ ln1g, const float* __restrict__ ln1b,
    const float* __restrict__ Wf1, const float* __restrict__ bf1,
    const float* __restrict__ Wf2, const float* __restrict__ bf2,
    const float* __restrict__ ln2g, const float* __restrict__ ln2b,
    float* __restrict__ out) {
  __shared__ float atts[2][DIMX];
  __shared__ float x1s[2][DIMX];
  __shared__ float hids[2][HID];
  __shared__ float4 red[16][2][64];  // 32 KB, reused across phases
  __shared__ float lr1[16], lr2[16];
  const int r0 = blockIdx.x * 2;
  const int tid = threadIdx.x;
  const int kc = tid >> 6;   // 16 k-chunks
  const int c4 = tid & 63;   // float4 col group
  const int rr = tid >> 8;   // 0..3
  const int c = tid & 255;

  if (tid < 512)
    atts[tid >> 8][tid & 255] = att[(r0 + (tid >> 8)) * DIMX + (tid & 255)];
  __syncthreads();

  // ---- out-proj (16-way k-split, float4) ----
  float4 a0 = {0.f, 0.f, 0.f, 0.f}, a1 = {0.f, 0.f, 0.f, 0.f};
  const float4* Wo4 = (const float4*)Wo;
#pragma unroll
  for (int i = 0; i < 16; ++i) {
    const int k = kc * 16 + i;
    const float4 w = Wo4[k * 64 + c4];
    const float v0 = atts[0][k], v1 = atts[1][k];
    a0.x += v0 * w.x; a0.y += v0 * w.y; a0.z += v0 * w.z; a0.w += v0 * w.w;
    a1.x += v1 * w.x; a1.y += v1 * w.y; a1.z += v1 * w.z; a1.w += v1 * w.w;
  }
  red[kc][0][c4] = a0;
  red[kc][1][c4] = a1;
  __syncthreads();
  for (int off = 8; off > 0; off >>= 1) {
    if (kc < off) {
      float4 p = red[kc][0][c4], q = red[kc + off][0][c4];
      p.x += q.x; p.y += q.y; p.z += q.z; p.w += q.w;
      red[kc][0][c4] = p;
      float4 p1 = red[kc][1][c4], q1 = red[kc + off][1][c4];
      p1.x += q1.x; p1.y += q1.y; p1.z += q1.z; p1.w += q1.w;
      red[kc][1][c4] = p1;
    }
    __syncthreads();
  }
  // ---- LN1 ----
  float t1 = 0.f;
  if (rr < 2) {
    const float4 v = red[0][rr][c >> 2];
    const float pv = ((const float*)&v)[c & 3];
    t1 = pv + x[(r0 + rr) * DIMX + c] + bo[c];
  }
  {
    float s1 = t1, s2 = t1 * t1;
    for (int off = 32; off > 0; off >>= 1) {
      s1 += __shfl_down(s1, off);
      s2 += __shfl_down(s2, off);
    }
    if ((tid & 63) == 0) { lr1[tid >> 6] = s1; lr2[tid >> 6] = s2; }
  }
  __syncthreads();
  if (rr < 2) {
    const int base = rr * 4;
    const float S1 = lr1[base] + lr1[base + 1] + lr1[base + 2] + lr1[base + 3];
    const float S2 = lr2[base] + lr2[base + 1] + lr2[base + 2] + lr2[base + 3];
    const float mu = S1 * (1.f / DIMX);
    const float var = S2 * (1.f / DIMX) - mu * mu;
    x1s[rr][c] = (t1 - mu) * rsqrtf(var + EPS) * ln1g[c] + ln1b[c];
  }
  __syncthreads();

  // ---- FFN1: hid = relu(x1 @ Wf1 + bf1), 4-way k-split, float4 cols ----
  {
    const int kc4 = tid >> 8;   // 0..3, k-chunk of 64
    const int t4 = tid & 255;   // hidden float4 group
    float4 h0 = {0.f, 0.f, 0.f, 0.f}, h1 = {0.f, 0.f, 0.f, 0.f};
    const float4* Wf14 = (const float4*)Wf1;
#pragma unroll 4
    for (int i = 0; i < 64; ++i) {
      const int k = kc4 * 64 + i;
      const float4 w = Wf14[k * 256 + t4];
      const float xv0 = x1s[0][k], xv1 = x1s[1][k];
      h0.x += xv0 * w.x; h0.y += xv0 * w.y; h0.z += xv0 * w.z; h0.w += xv0 * w.w;
      h1.x += xv1 * w.x; h1.y += xv1 * w.y; h1.z += xv1 * w.z; h1.w += xv1 * w.w;
    }
    float4 (*redF)[2][256] = (float4(*)[2][256])red;
    redF[kc4][0][t4] = h0;
    redF[kc4][1][t4] = h1;
  }
  __syncthreads();
  if (tid < 512) {
    const int r_ = tid >> 8;
    const int t4 = tid & 255;
    float4 (*redF)[2][256] = (float4(*)[2][256])red;
    float4 s = redF[0][r_][t4];
    const float4 s1_ = redF[1][r_][t4], s2_ = redF[2][r_][t4], s3_ = redF[3][r_][t4];
    s.x += s1_.x + s2_.x + s3_.x;
    s.y += s1_.y + s2_.y + s3_.y;
    s.z += s1_.z + s2_.z + s3_.z;
    s.w += s1_.w + s2_.w + s3_.w;
    const float4 bf = ((const float4*)bf1)[t4];
    hids[r_][t4 * 4 + 0] = fmaxf(s.x + bf.x, 0.f);
    hids[r_][t4 * 4 + 1] = fmaxf(s.y + bf.y, 0.f);
    hids[r_][t4 * 4 + 2] = fmaxf(s.z + bf.z, 0.f);
    hids[r_][t4 * 4 + 3] = fmaxf(s.w + bf.w, 0.f);
  }
  __syncthreads();

  // ---- FFN2 (16-way k-split, float4) ----
  float4 b0 = {0.f, 0.f, 0.f, 0.f}, b1_ = {0.f, 0.f, 0.f, 0.f};
  const float4* W4 = (const float4*)Wf2;
#pragma unroll 4
  for (int i = 0; i < 64; ++i) {
    const int k = kc * 64 + i;
    const float4 w = W4[k * 64 + c4];
    const float h0 = hids[0][k], h1 = hids[1][k];
    b0.x += h0 * w.x; b0.y += h0 * w.y; b0.z += h0 * w.z; b0.w += h0 * w.w;
    b1_.x += h1 * w.x; b1_.y += h1 * w.y; b1_.z += h1 * w.z; b1_.w += h1 * w.w;
  }
  red[kc][0][c4] = b0;
  red[kc][1][c4] = b1_;
  __syncthreads();
  for (int off = 8; off > 0; off >>= 1) {
    if (kc < off) {
      float4 p = red[kc][0][c4], q = red[kc + off][0][c4];
      p.x += q.x; p.y += q.y; p.z += q.z; p.w += q.w;
      red[kc][0][c4] = p;
      float4 p1 = red[kc][1][c4], q1 = red[kc + off][1][c4];
      p1.x += q1.x; p1.y += q1.y; p1.z += q1.z; p1.w += q1.w;
      red[kc][1][c4] = p1;
    }
    __syncthreads();
  }
  // ---- LN2 ----
  float t2 = 0.f;
  if (rr < 2) {
    const float4 v = red[0][rr][c >> 2];
    const float pv = ((const float*)&v)[c & 3];
    t2 = pv + x1s[rr][c] + bf2[c];
  }
  {
    float s1 = t2, s2 = t2 * t2;
    for (int off = 32; off > 0; off >>= 1) {
      s1 += __shfl_down(s1, off);
      s2 += __shfl_down(s2, off);
    }
    if ((tid & 63) == 0) { lr1[tid >> 6] = s1; lr2[tid >> 6] = s2; }
  }
  __syncthreads();
  if (rr < 2) {
    const int base = rr * 4;
    const float S1 = lr1[base] + lr1[base + 1] + lr1[base + 2] + lr1[base + 3];
    const float S2 = lr2[base] + lr2[base + 1] + lr2[base + 2] + lr2[base + 3];
    const float mu = S1 * (1.f / DIMX);
    const float var = S2 * (1.f / DIMX) - mu * mu;
    out[(r0 + rr) * DIMX + c] = (t2 - mu) * rsqrtf(var + EPS) * ln2g[c] + ln2b[c];
  }
}

extern "C" void kernel_launch(void* const* d_in, const int* in_sizes, int n_in,
                              void* d_out, int out_size, void* d_ws,
                              size_t ws_size, hipStream_t stream) {
  const float* x = (const float*)d_in[0];
  const float* pos = (const float*)d_in[1];
  const int* mask = (const int*)d_in[2];
  const float* Wqkv = (const float*)d_in[3];
  const float* bqkv = (const float*)d_in[4];
  const float* W1 = (const float*)d_in[5];
  const float* b1 = (const float*)d_in[6];
  const float* W2 = (const float*)d_in[7];
  const float* b2 = (const float*)d_in[8];
  const float* Wo = (const float*)d_in[9];
  const float* bo = (const float*)d_in[10];
  const float* ln1g = (const float*)d_in[11];
  const float* ln1b = (const float*)d_in[12];
  const float* Wf1 = (const float*)d_in[13];
  const float* bf1 = (const float*)d_in[14];
  const float* Wf2 = (const float*)d_in[15];
  const float* bf2 = (const float*)d_in[16];
  const float* ln2g = (const float*)d_in[17];
  const float* ln2b = (const float*)d_in[18];

  float* ws = (float*)d_ws;
  float* kk = ws + OFF_KK;
  float2* qv2 = (float2*)(ws + OFF_QV);
  float* t_sorted = ws + OFF_TSORT;
  int* idx_sorted = (int*)(ws + OFF_IDX);
  float2* SC = (float2*)(ws + OFF_SC);
  float* att = ws + OFF_ATT;
  float* outp = (float*)d_out;

  hipLaunchKernelGGL(prep_kernel, dim3(208), dim3(1024), 0, stream, x, Wqkv,
                     bqkv, W1, b1, kk, qv2, t_sorted, idx_sorted);
  hipLaunchKernelGGL(scan_kernel, dim3(DIMX), dim3(1024), 0, stream, W1, b1,
                     W2, b2, idx_sorted, SC);
  hipLaunchKernelGGL(attn_kernel, dim3(NROWS), dim3(1024), 0, stream, pos,
                     mask, kk, qv2, t_sorted, SC, att);
  hipLaunchKernelGGL(tail_kernel, dim3(NROWS / 2), dim3(1024), 0, stream, att,
                     x, Wo, bo, ln1g, ln1b, Wf1, bf1, Wf2, bf2, ln2g, ln2b,
                     outp);
}

// Round 5
// 95.467 us; speedup vs baseline: 3.9463x; 1.1628x over previous
//
#include <hip/hip_runtime.h>
#include <math.h>

#define NB 2
#define NN 192
#define DIMX 256
#define HID 1024
#define NROWS (NB * NN)            // 384
#define SCALING 0.17677669529663687f  // 1/sqrt(32)
#define EPS 1e-5f

// workspace layout (float offsets)
#define OFF_KK    0                              // k-part, NROWS*256
#define OFF_QV    (OFF_KK + NROWS * DIMX)        // float2 q,v  NROWS*256*2
#define OFF_TSORT (OFF_QV + NROWS * DIMX * 2)    // 1024
#define OFF_IDX   (OFF_TSORT + HID)              // 1024 ints
#define OFF_SC    (OFF_IDX + HID)                // float2 (HID+1)*256*2
#define OFF_ATT   (OFF_SC + (HID + 1) * DIMX * 2)
// end = OFF_ATT + NROWS*DIMX = 920,064 floats ≈ 3.7 MB

// ---------------- K1: prep = qkv GEMM (blocks 0..191) + sortrank (192..207)
__global__ __launch_bounds__(1024) void prep_kernel(
    const float* __restrict__ x, const float* __restrict__ Wqkv,
    const float* __restrict__ bqkv, const float* __restrict__ W1,
    const float* __restrict__ b1, float* __restrict__ kk,
    float2* __restrict__ qv2, float* __restrict__ t_sorted,
    int* __restrict__ idx_sorted) {
  __shared__ float xs[2][DIMX];
  __shared__ float red[2][2][768];  // 12 KB
  __shared__ float ts[HID];
  __shared__ int part[64][17];
  const int tid = threadIdx.x;
  if (blockIdx.x < 192) {
    const int r0 = blockIdx.x * 2;
    const int c = tid & 255;
    const int rr = (tid >> 8) & 1;
    const int kc = tid >> 9;
    if (tid < 512)
      xs[tid >> 8][tid & 255] = x[(r0 + (tid >> 8)) * DIMX + (tid & 255)];
    __syncthreads();
    float a0 = 0.f, a1 = 0.f, a2 = 0.f;
    const int k0 = kc * 128;
#pragma unroll 4
    for (int i = 0; i < 128; ++i) {
      const int k = k0 + i;
      const float xv = xs[rr][k];
      a0 += xv * Wqkv[k * 768 + c];
      a1 += xv * Wqkv[k * 768 + 256 + c];
      a2 += xv * Wqkv[k * 768 + 512 + c];
    }
    red[kc][rr][c] = a0;
    red[kc][rr][256 + c] = a1;
    red[kc][rr][512 + c] = a2;
    __syncthreads();
    if (kc == 0) {
      const int row = r0 + rr;
      kk[row * DIMX + c] = red[0][rr][256 + c] + red[1][rr][256 + c] + bqkv[256 + c];
      const float q = red[0][rr][c] + red[1][rr][c] + bqkv[c];
      const float v = red[0][rr][512 + c] + red[1][rr][512 + c] + bqkv[512 + c];
      qv2[row * DIMX + c] = make_float2(q, v);
    }
  } else {
    const int bk = blockIdx.x - 192;
    {
      const float w = W1[tid];
      ts[tid] = (w != 0.f) ? (-b1[tid] / w) : INFINITY;
    }
    __syncthreads();
    const int hl = tid >> 4;
    const int ck = tid & 15;
    const int h = bk * 64 + hl;
    const float t = ts[h];
    int cnt = 0;
    const int r0 = ck * 64;
#pragma unroll 4
    for (int rr = 0; rr < 64; ++rr) {
      const int r = r0 + rr;
      const float tv = ts[r];
      cnt += ((tv < t) || (tv == t && r < h)) ? 1 : 0;
    }
    part[hl][ck] = cnt;
    __syncthreads();
    if (ck == 0) {
      int rank = 0;
#pragma unroll
      for (int u = 0; u < 16; ++u) rank += part[hl][u];
      t_sorted[rank] = t;
      idx_sorted[rank] = h;
    }
  }
}

// ------- K2: baseline + deltas + wave-shuffle inclusive scan -> SC table ----
__global__ __launch_bounds__(1024) void scan_kernel(
    const float* __restrict__ W1, const float* __restrict__ b1,
    const float* __restrict__ W2, const float* __restrict__ b2,
    const int* __restrict__ idx_sorted, float2* __restrict__ SC) {
  const int c = blockIdx.x;
  const int tid = threadIdx.x;
  const int lane = tid & 63;
  const int wid = tid >> 6;
  __shared__ float sW1[HID];
  __shared__ float sb1[HID];
  __shared__ int sidx[HID];
  __shared__ float bws[16], bwc[16], tws[16], twc[16];

  const float w = W1[tid];
  const float b1s = b1[tid];
  sW1[tid] = w;
  sb1[tid] = b1s;
  sidx[tid] = idx_sorted[tid];

  // baseline contribution (active set at d = -inf)
  float bs = 0.f, bc = 0.f;
  {
    const float w2v = W2[tid * DIMX + c];
    if (w < 0.f) {
      bs = w * w2v;
      bc = b1s * w2v;
    } else if (w == 0.f && b1s > 0.f) {
      bc = b1s * w2v;
    }
  }
  for (int off = 32; off > 0; off >>= 1) {
    bs += __shfl_down(bs, off);
    bc += __shfl_down(bc, off);
  }
  __syncthreads();  // sW1/sb1/sidx ready

  // per-segment delta (sorted order s = tid)
  float vS, vC;
  {
    const int hh = sidx[tid];
    const float w1v = sW1[hh];
    const float sign = (w1v > 0.f) ? 1.f : -1.f;
    const float coefS = (w1v == 0.f) ? 0.f : sign * w1v;
    const float coefC = (w1v == 0.f) ? 0.f : sign * sb1[hh];
    const float w2v = W2[hh * DIMX + c];
    vS = coefS * w2v;
    vC = coefC * w2v;
  }
  // wave-inclusive scan
  for (int off = 1; off < 64; off <<= 1) {
    const float tS_ = __shfl_up(vS, off);
    const float tC_ = __shfl_up(vC, off);
    if (lane >= off) {
      vS += tS_;
      vC += tC_;
    }
  }
  if (lane == 0) {
    bws[wid] = bs;
    bwc[wid] = bc;
  }
  if (lane == 63) {
    tws[wid] = vS;
    twc[wid] = vC;
  }
  __syncthreads();
  float S0 = 0.f, C0 = 0.f, offS = 0.f, offC = 0.f;
#pragma unroll
  for (int u = 0; u < 16; ++u) {
    S0 += bws[u];
    C0 += bwc[u];
    if (u < wid) {
      offS += tws[u];
      offC += twc[u];
    }
  }
  C0 += b2[c];
  SC[(tid + 1) * DIMX + c] = make_float2(S0 + offS + vS, C0 + offC + vC);
  if (tid == 0) SC[c] = make_float2(S0, C0);
}

// ------- K3: fused distance-attention, 4-way j-split, no-max softmax -------
__global__ __launch_bounds__(1024) void attn_kernel(
    const float* __restrict__ pos, const int* __restrict__ mask,
    const float* __restrict__ kk, const float2* __restrict__ qv2,
    const float* __restrict__ t_sorted, const float2* __restrict__ SC,
    float* __restrict__ att) {
  __shared__ float tS[HID];
  __shared__ float posB[NN][3];
  __shared__ int maskB[NN];
  __shared__ float dJ[NN];
  __shared__ float decJ[NN];
  __shared__ int segJ[NN];
  __shared__ int pmJ[NN];
  __shared__ float sl[4][DIMX];
  __shared__ float so[4][DIMX];

  const int r = blockIdx.x;
  const int b = r / NN;
  const int i = r % NN;
  const int tid = threadIdx.x;
  const int c = tid & 255;
  const int jq = tid >> 8;

  tS[tid] = t_sorted[tid];
  if (tid < NN) {
    posB[tid][0] = pos[(b * NN + tid) * 3 + 0];
    posB[tid][1] = pos[(b * NN + tid) * 3 + 1];
    posB[tid][2] = pos[(b * NN + tid) * 3 + 2];
    maskB[tid] = mask[b * NN + tid];
  }
  __syncthreads();

  if (tid < NN) {
    const int j = tid;
    const float dx = posB[j][0] - posB[i][0];
    const float dy = posB[j][1] - posB[i][1];
    const float dz = posB[j][2] - posB[i][2];
    const float sq = dx * dx + dy * dy + dz * dz;
    const float d = (sq > 0.f) ? sqrtf(sq) : 0.f;
    dJ[j] = d;
    decJ[j] = __expf(-sq * 0.1f);
    int lo = 0, hi = HID;
    while (lo < hi) {
      const int mid = (lo + hi) >> 1;
      if (tS[mid] <= d) lo = mid + 1;
      else hi = mid;
    }
    segJ[j] = lo;
    pmJ[j] = maskB[i] && maskB[j];
  }
  __syncthreads();

  const float kc_ = kk[(b * NN + i) * DIMX + c];
  float l = 0.f, o = 0.f;
  const int j0 = jq * 48;
#pragma unroll 4
  for (int jj = 0; jj < 48; ++jj) {
    const int j = j0 + jj;
    const int seg = segJ[j];
    const float2 sc = SC[seg * DIMX + c];
    const float de = sc.y + dJ[j] * sc.x;
    const float2 qv = qv2[(b * NN + j) * DIMX + c];
    const float sval = decJ[j] * (kc_ + de) * (qv.x * SCALING);
    const float p = pmJ[j] ? 0.f : __expf(sval);
    l += p;
    o += p * qv.y;
  }
  sl[jq][c] = l;
  so[jq][c] = o;
  __syncthreads();
  if (tid < DIMX) {
    const float lt = sl[0][tid] + sl[1][tid] + sl[2][tid] + sl[3][tid];
    const float ot = so[0][tid] + so[1][tid] + so[2][tid] + so[3][tid];
    att[r * DIMX + tid] = ot / lt;
  }
}

// ------- K4: fused tail (4 rows/block, float4 weights, k-split in wave) ----
__global__ __launch_bounds__(1024) void tail_kernel(
    const float* __restrict__ att, const float* __restrict__ x,
    const float* __restrict__ Wo, const float* __restrict__ bo,
    const float* __restrict__ ln1g, const float* __restrict__ ln1b,
    const float* __restrict__ Wf1, const float* __restrict__ bf1,
    const float* __restrict__ Wf2, const float* __restrict__ bf2,
    const float* __restrict__ ln2g, const float* __restrict__ ln2b,
    float* __restrict__ out) {
  __shared__ float atts[4][DIMX];     // 4 KB
  __shared__ float x1sT[DIMX][4];     // 4 KB (transposed: [k][row])
  __shared__ float hidsT[HID][4];     // 16 KB (transposed: [t][row])
  __shared__ float4 red[16][4][64];   // 64 KB, reused across phases
  __shared__ float lr1[16], lr2[16];
  const int r0 = blockIdx.x * 4;
  const int tid = threadIdx.x;
  const int rr = tid >> 8;   // 0..3 row
  const int c = tid & 255;   // channel

  atts[rr][c] = att[(r0 + rr) * DIMX + c];
  const float xr = x[(r0 + rr) * DIMX + c];
  __syncthreads();

  // ---- proj: (rr, ks=(tid>>6)&3, c4=tid&63), 64 float4 loads ----
  {
    const int ks = (tid >> 6) & 3;
    const int c4 = tid & 63;
    const float4* Wo4 = (const float4*)Wo;
    float4 acc = {0.f, 0.f, 0.f, 0.f};
#pragma unroll 8
    for (int i = 0; i < 64; ++i) {
      const int k = ks * 64 + i;
      const float4 w = Wo4[k * 64 + c4];
      const float av = atts[rr][k];
      acc.x += av * w.x; acc.y += av * w.y; acc.z += av * w.z; acc.w += av * w.w;
    }
    red[ks][rr][c4] = acc;
  }
  __syncthreads();
  float t1;
  {
    const int c4 = c >> 2, cm = c & 3;
    const float pv = ((const float*)&red[0][rr][c4])[cm] +
                     ((const float*)&red[1][rr][c4])[cm] +
                     ((const float*)&red[2][rr][c4])[cm] +
                     ((const float*)&red[3][rr][c4])[cm];
    t1 = pv + xr + bo[c];
  }
  // ---- LN1 (per-row: waves 4rr..4rr+3) ----
  {
    float s1 = t1, s2 = t1 * t1;
    for (int off = 32; off > 0; off >>= 1) {
      s1 += __shfl_down(s1, off);
      s2 += __shfl_down(s2, off);
    }
    if ((tid & 63) == 0) { lr1[tid >> 6] = s1; lr2[tid >> 6] = s2; }
  }
  __syncthreads();
  float x1;
  {
    const int base = rr * 4;
    const float S1 = lr1[base] + lr1[base + 1] + lr1[base + 2] + lr1[base + 3];
    const float S2 = lr2[base] + lr2[base + 1] + lr2[base + 2] + lr2[base + 3];
    const float mu = S1 * (1.f / DIMX);
    const float var = S2 * (1.f / DIMX) - mu * mu;
    x1 = (t1 - mu) * rsqrtf(var + EPS) * ln1g[c] + ln1b[c];
  }
  x1sT[c][rr] = x1;
  __syncthreads();

  // ---- FFN1: (ks=tid>>8, h4=tid&255); Wf1 read once; 16 FMA / load ----
  {
    const int ks = tid >> 8;
    const int h4 = tid & 255;
    const float4* Wf14 = (const float4*)Wf1;
    float4 h0 = {0.f,0.f,0.f,0.f}, h1 = {0.f,0.f,0.f,0.f};
    float4 h2 = {0.f,0.f,0.f,0.f}, h3 = {0.f,0.f,0.f,0.f};
#pragma unroll 4
    for (int i = 0; i < 64; ++i) {
      const int k = ks * 64 + i;
      const float4 w = Wf14[k * 256 + h4];
      const float4 xv = *(const float4*)&x1sT[k][0];
      h0.x += xv.x * w.x; h0.y += xv.x * w.y; h0.z += xv.x * w.z; h0.w += xv.x * w.w;
      h1.x += xv.y * w.x; h1.y += xv.y * w.y; h1.z += xv.y * w.z; h1.w += xv.y * w.w;
      h2.x += xv.z * w.x; h2.y += xv.z * w.y; h2.z += xv.z * w.z; h2.w += xv.z * w.w;
      h3.x += xv.w * w.x; h3.y += xv.w * w.y; h3.z += xv.w * w.z; h3.w += xv.w * w.w;
    }
    float4 (*redF)[4][256] = (float4(*)[4][256])red;
    redF[ks][0][h4] = h0;
    redF[ks][1][h4] = h1;
    redF[ks][2][h4] = h2;
    redF[ks][3][h4] = h3;
  }
  __syncthreads();
  {
    const int hh = tid;
    const int h4 = hh >> 2, cm = hh & 3;
    const float bf = bf1[hh];
    float4 (*redF)[4][256] = (float4(*)[4][256])red;
#pragma unroll
    for (int r_ = 0; r_ < 4; ++r_) {
      const float v = ((const float*)&redF[0][r_][h4])[cm] +
                      ((const float*)&redF[1][r_][h4])[cm] +
                      ((const float*)&redF[2][r_][h4])[cm] +
                      ((const float*)&redF[3][r_][h4])[cm];
      hidsT[hh][r_] = fmaxf(v + bf, 0.f);
    }
  }
  __syncthreads();

  // ---- FFN2: (ks=tid>>6 (16), c4=tid&63); Wf2 read once; 16 FMA / load ----
  {
    const int ks = tid >> 6;
    const int c4 = tid & 63;
    const float4* Wf24 = (const float4*)Wf2;
    float4 a0 = {0.f,0.f,0.f,0.f}, a1 = {0.f,0.f,0.f,0.f};
    float4 a2 = {0.f,0.f,0.f,0.f}, a3 = {0.f,0.f,0.f,0.f};
#pragma unroll 4
    for (int i = 0; i < 64; ++i) {
      const int k = ks * 64 + i;
      const float4 w = Wf24[k * 64 + c4];
      const float4 hv = *(const float4*)&hidsT[k][0];
      a0.x += hv.x * w.x; a0.y += hv.x * w.y; a0.z += hv.x * w.z; a0.w += hv.x * w.w;
      a1.x += hv.y * w.x; a1.y += hv.y * w.y; a1.z += hv.y * w.z; a1.w += hv.y * w.w;
      a2.x += hv.z * w.x; a2.y += hv.z * w.y; a2.z += hv.z * w.z; a2.w += hv.z * w.w;
      a3.x += hv.w * w.x; a3.y += hv.w * w.y; a3.z += hv.w * w.z; a3.w += hv.w * w.w;
    }
    red[ks][0][c4] = a0;
    red[ks][1][c4] = a1;
    red[ks][2][c4] = a2;
    red[ks][3][c4] = a3;
  }
  __syncthreads();
  float t2;
  {
    const int c4 = c >> 2, cm = c & 3;
    float pv = 0.f;
#pragma unroll
    for (int u = 0; u < 16; ++u) pv += ((const float*)&red[u][rr][c4])[cm];
    t2 = pv + x1 + bf2[c];
  }
  // ---- LN2 ----
  {
    float s1 = t2, s2 = t2 * t2;
    for (int off = 32; off > 0; off >>= 1) {
      s1 += __shfl_down(s1, off);
      s2 += __shfl_down(s2, off);
    }
    if ((tid & 63) == 0) { lr1[tid >> 6] = s1; lr2[tid >> 6] = s2; }
  }
  __syncthreads();
  {
    const int base = rr * 4;
    const float S1 = lr1[base] + lr1[base + 1] + lr1[base + 2] + lr1[base + 3];
    const float S2 = lr2[base] + lr2[base + 1] + lr2[base + 2] + lr2[base + 3];
    const float mu = S1 * (1.f / DIMX);
    const float var = S2 * (1.f / DIMX) - mu * mu;
    out[(r0 + rr) * DIMX + c] = (t2 - mu) * rsqrtf(var + EPS) * ln2g[c] + ln2b[c];
  }
}

extern "C" void kernel_launch(void* const* d_in, const int* in_sizes, int n_in,
                              void* d_out, int out_size, void* d_ws,
                              size_t ws_size, hipStream_t stream) {
  const float* x = (const float*)d_in[0];
  const float* pos = (const float*)d_in[1];
  const int* mask = (const int*)d_in[2];
  const float* Wqkv = (const float*)d_in[3];
  const float* bqkv = (const float*)d_in[4];
  const float* W1 = (const float*)d_in[5];
  const float* b1 = (const float*)d_in[6];
  const float* W2 = (const float*)d_in[7];
  const float* b2 = (const float*)d_in[8];
  const float* Wo = (const float*)d_in[9];
  const float* bo = (const float*)d_in[10];
  const float* ln1g = (const float*)d_in[11];
  const float* ln1b = (const float*)d_in[12];
  const float* Wf1 = (const float*)d_in[13];
  const float* bf1 = (const float*)d_in[14];
  const float* Wf2 = (const float*)d_in[15];
  const float* bf2 = (const float*)d_in[16];
  const float* ln2g = (const float*)d_in[17];
  const float* ln2b = (const float*)d_in[18];

  float* ws = (float*)d_ws;
  float* kk = ws + OFF_KK;
  float2* qv2 = (float2*)(ws + OFF_QV);
  float* t_sorted = ws + OFF_TSORT;
  int* idx_sorted = (int*)(ws + OFF_IDX);
  float2* SC = (float2*)(ws + OFF_SC);
  float* att = ws + OFF_ATT;
  float* outp = (float*)d_out;

  hipLaunchKernelGGL(prep_kernel, dim3(208), dim3(1024), 0, stream, x, Wqkv,
                     bqkv, W1, b1, kk, qv2, t_sorted, idx_sorted);
  hipLaunchKernelGGL(scan_kernel, dim3(DIMX), dim3(1024), 0, stream, W1, b1,
                     W2, b2, idx_sorted, SC);
  hipLaunchKernelGGL(attn_kernel, dim3(NROWS), dim3(1024), 0, stream, pos,
                     mask, kk, qv2, t_sorted, SC, att);
  hipLaunchKernelGGL(tail_kernel, dim3(NROWS / 4), dim3(1024), 0, stream, att,
                     x, Wo, bo, ln1g, ln1b, Wf1, bf1, Wf2, bf2, ln2g, ln2b,
                     outp);
}